// Round 4
// baseline (304.733 us; speedup 1.0000x reference)
//
#include <hip/hip_runtime.h>
#include <hip/hip_bf16.h>

// Effi_MVS: B=1, V=5, C=32, D=48, H=128, W=160, RATIO=8.
// Round 7: R6 post-mortem — k_warpvar is stall-bound (VALU floor ~15us,
// measured 139us; no pipe >40%). The gather has massive depth-reuse:
// gy==y exactly and per-view x-shift = 400v/df in [0.4, 3.8] px, so all
// 48 depths of a (y, 16-x-span) tile read the same <=26-float row segments
// of the 5 feature planes.
//   Restructure: block = 768 threads (16 x * 48 d), stage [32c][5v][26col]
//   (16.6 KB) to LDS once, hot loop reads LDS (latency 120 vs 300-900 cyc,
//   ~6 cyc throughput). Wave count unchanged (60/CU; R5's TLP lesson).
//   Per-thread fallback to R6's 4-tap global path when a tap leaves the
//   staged window (general inputs / the single plane-end corner voxel).

#define NV 5
#define NC 32
#define ND 48
#define NH 128
#define NW 160
#define HW (NH * NW)
#define DHW (ND * HW)

#define XSPAN 16
#define SCOLS 26
#define BTHREADS (XSPAN * ND)   // 768

typedef __attribute__((ext_vector_type(2))) float f32x2;
typedef __attribute__((ext_vector_type(4))) float f32x4;
typedef __attribute__((ext_vector_type(2), aligned(4))) float f32x2u;

// ws layout (bytes)
#define OFF_M      0          // float M[4][12]
#define OFF_WF     256        // float wf[32][28]
#define OFF_DEPTHF 4096       // float depthf[20480]
#define OFF_PRE    86016      // float pre[48*128*160]
#define OFF_WV     4018176    // bf16 WV[27][48*128*160]
// total = 57,102,336 bytes

// ---------------------------------------------------------------- K1: setup
__global__ void k_setup(const float* __restrict__ proj,
                        const float* __restrict__ wreg,
                        float* __restrict__ M, float* __restrict__ wf) {
  if (threadIdx.x != 0) return;
  double P[NV][2][4][4];
  for (int v = 0; v < NV; ++v)
    for (int m = 0; m < 2; ++m)
      for (int i = 0; i < 4; ++i)
        for (int j = 0; j < 4; ++j)
          P[v][m][i][j] = (double)proj[((v * 2 + m) * 4 + i) * 4 + j];
  double C[NV][4][4];
  for (int v = 0; v < NV; ++v) {
    for (int i = 0; i < 4; ++i)
      for (int j = 0; j < 4; ++j) C[v][i][j] = P[v][0][i][j];
    for (int i = 0; i < 3; ++i)
      for (int j = 0; j < 4; ++j) {
        double s = 0.0;
        for (int k = 0; k < 3; ++k) s += P[v][1][i][k] * P[v][0][k][j];
        C[v][i][j] = s;
      }
  }
  double a[4][8];
  for (int i = 0; i < 4; ++i)
    for (int j = 0; j < 4; ++j) { a[i][j] = C[0][i][j]; a[i][j + 4] = (i == j) ? 1.0 : 0.0; }
  for (int col = 0; col < 4; ++col) {
    int piv = col; double best = fabs(a[col][col]);
    for (int r = col + 1; r < 4; ++r) { double v = fabs(a[r][col]); if (v > best) { best = v; piv = r; } }
    if (piv != col)
      for (int j = 0; j < 8; ++j) { double t = a[col][j]; a[col][j] = a[piv][j]; a[piv][j] = t; }
    double pv = a[col][col];
    for (int j = 0; j < 8; ++j) a[col][j] /= pv;
    for (int r = 0; r < 4; ++r) if (r != col) {
      double f = a[r][col];
      for (int j = 0; j < 8; ++j) a[r][j] -= f * a[col][j];
    }
  }
  double inv[4][4];
  for (int i = 0; i < 4; ++i)
    for (int j = 0; j < 4; ++j) inv[i][j] = a[i][j + 4];
  for (int v = 1; v < NV; ++v) {
    float* m = M + (v - 1) * 12;
    for (int i = 0; i < 3; ++i) {
      double r[4] = {0, 0, 0, 0};
      for (int k = 0; k < 4; ++k) {
        double cv = C[v][i][k];
        for (int j = 0; j < 4; ++j) r[j] += cv * inv[k][j];
      }
      m[i * 3 + 0] = (float)r[0]; m[i * 3 + 1] = (float)r[1]; m[i * 3 + 2] = (float)r[2];
      m[9 + i] = (float)r[3];
    }
  }
  for (int c = 0; c < NC; ++c) {
    for (int t = 0; t < 27; ++t) wf[c * 28 + t] = wreg[c * 27 + t];
    wf[c * 28 + 27] = 0.f;
  }
}

// ------------------------------------------- K2: warp + variance + contract
__global__ __launch_bounds__(BTHREADS) void k_warpvar(
    const float* __restrict__ feat,    // [5][32][128][160]
    const float* __restrict__ depthv,  // [48]
    const float* __restrict__ M,       // [4][12]
    const float* __restrict__ wf,      // [32][28]
    __hip_bfloat16* __restrict__ WV)   // [27][DHW]
{
  __shared__ float stage[NC * NV * SCOLS];   // [c][v][26] = 16,640 B

  int tid = threadIdx.x;
  int bx = blockIdx.x % (NW / XSPAN);
  int y  = blockIdx.x / (NW / XSPAN);
  int x0b = bx * XSPAN;

  // ---- stage the 5 planes' row-y segments [x0b, x0b+26) for all channels
  for (int lin = tid; lin < NC * NV * SCOLS; lin += BTHREADS) {
    int col = lin % SCOLS;
    int r   = lin / SCOLS;
    int v   = r % NV;
    int c   = r / NV;
    int gxc = x0b + col;
    float val = 0.f;
    if (gxc < NW) val = feat[(v * NC + c) * HW + y * NW + gxc];
    stage[(c * NV + v) * SCOLS + col] = val;
  }

  // ---- per-thread tap state (2-tap LDS form) + eligibility
  int x = x0b + (tid & (XSPAN - 1));
  int d = tid >> 4;                         // 0..47
  float xf = (float)x, yf = (float)y;
  float df = depthv[d];

  int   lcol[4];
  float wA[4], wB[4];
  bool fast = true;

#pragma unroll
  for (int v = 0; v < 4; ++v) {
    const float* m = M + v * 12;
    float rx = m[0] * xf + m[1] * yf + m[2];
    float ry = m[3] * xf + m[4] * yf + m[5];
    float rz = m[6] * xf + m[7] * yf + m[8];
    float px = rx * df + m[9];
    float py = ry * df + m[10];
    float pz = rz * df + m[11];
    float gx = px / pz;
    float gy = py / pz;
    float y0 = floorf(gy);
    float wy = gy - y0;
    bool two = (wy == 0.f) || (wy == 1.f);
    float rowf = (wy == 0.f) ? y0 : (y0 + 1.f);  // single surviving y-row
    float x0 = floorf(gx);
    float wx = gx - x0;
    bool yok  = (rowf >= 0.f) && (rowf <= (float)(NH - 1));
    bool x0ok = (x0 >= 0.f) && (x0 <= (float)(NW - 1)) && yok;
    bool x1ok = (x0 >= -1.f) && (x0 <= (float)(NW - 2)) && yok;
    float rc = fminf(fmaxf(rowf, 0.f), (float)(NH - 1));
    float xc = fminf(fmaxf(x0, 0.f), (float)(NW - 1));
    int xi = (int)xc;
    bool sv = (x0 >= 0.f) && (xi <= NW - 2);   // e.y is the distinct tap1
    float w0 = (1.f - wx) * (x0ok ? 1.f : 0.f);
    float w1 = wx * (x1ok ? 1.f : 0.f);
    // val = wA*e.x + wB*e.y; clamped/one-tap cases fold into weights.
    // (zero-padded stage guarantees e.y is finite when wB==0)
    wA[v] = sv ? w0 : (w0 + w1);
    wB[v] = sv ? w1 : 0.f;
    int lc = xi - x0b;
    lcol[v] = lc;
    bool ddv = (xi == NW - 1) && ((int)rc == NH - 1);  // plane-end corner
    fast = fast && two && (rc == yf) && (lc >= 0) && (lc <= SCOLS - 2) && !ddv;
  }

  __syncthreads();

  int idx = d * HW + y * NW + x;
  f32x2 wv[14];
#pragma unroll
  for (int u = 0; u < 14; ++u) { wv[u].x = 0.f; wv[u].y = 0.f; }

  if (__builtin_expect(fast, 1)) {
    // ---------- hot path: all taps from LDS
    const float* s0 = stage + (x - x0b);
#pragma unroll
    for (int c = 0; c < NC; ++c) {
      const float* sc = s0 + c * (NV * SCOLS);
      float f0 = sc[0];
      float vs = f0, vq = f0 * f0;
#pragma unroll
      for (int v = 0; v < 4; ++v) {
        const float* sv_ = stage + c * (NV * SCOLS) + (v + 1) * SCOLS + lcol[v];
        f32x2u e = *(const f32x2u*)sv_;
        float val = wA[v] * e.x + wB[v] * e.y;
        vs += val;
        vq += val * val;
      }
      float var = vq * 0.2f - (vs * 0.2f) * (vs * 0.2f);
      const f32x2* wrow = (const f32x2*)(wf + c * 28);
      f32x2 vv; vv.x = var; vv.y = var;
#pragma unroll
      for (int u = 0; u < 14; ++u) wv[u] += wrow[u] * vv;
    }
  } else {
    // ---------- general 4-tap global fallback (cold). v/u unrolled, c rolled.
    int pix = y * NW + x;
    int cidx[16]; float cw[16];
#pragma unroll
    for (int v = 0; v < 4; ++v) {
      const float* m = M + v * 12;
      float rx = m[0] * xf + m[1] * yf + m[2];
      float ry = m[3] * xf + m[4] * yf + m[5];
      float rz = m[6] * xf + m[7] * yf + m[8];
      float px = rx * df + m[9];
      float py = ry * df + m[10];
      float pz = rz * df + m[11];
      float gx = px / pz;
      float gy = py / pz;
      float x0 = floorf(gx), y0 = floorf(gy);
      float wx = gx - x0, wy = gy - y0;
      float cxs[2] = {x0, x0 + 1.f}, cys[2] = {y0, y0 + 1.f};
      float wxs[2] = {1.f - wx, wx}, wys[2] = {1.f - wy, wy};
#pragma unroll
      for (int cy = 0; cy < 2; ++cy)
#pragma unroll
        for (int cx = 0; cx < 2; ++cx) {
          float fx = cxs[cx], fy = cys[cy];
          bool valid = (fx >= 0.f) && (fx <= (float)(NW - 1)) &&
                       (fy >= 0.f) && (fy <= (float)(NH - 1));
          float fxc = fminf(fmaxf(fx, 0.f), (float)(NW - 1));
          float fyc = fminf(fmaxf(fy, 0.f), (float)(NH - 1));
          int xi2 = (int)fxc, yi2 = (int)fyc;
          cidx[v * 4 + cy * 2 + cx] = yi2 * NW + xi2;
          cw[v * 4 + cy * 2 + cx] = wxs[cx] * wys[cy] * (valid ? 1.f : 0.f);
        }
    }
    for (int c = 0; c < NC; ++c) {
      float f0 = feat[c * HW + pix];
      float vs = f0, vq = f0 * f0;
#pragma unroll
      for (int v = 0; v < 4; ++v) {
        const float* fv = feat + ((v + 1) * NC + c) * HW;
        float val = cw[v * 4 + 0] * fv[cidx[v * 4 + 0]]
                  + cw[v * 4 + 1] * fv[cidx[v * 4 + 1]]
                  + cw[v * 4 + 2] * fv[cidx[v * 4 + 2]]
                  + cw[v * 4 + 3] * fv[cidx[v * 4 + 3]];
        vs += val;
        vq += val * val;
      }
      float var = vq * 0.2f - (vs * 0.2f) * (vs * 0.2f);
      const f32x2* wrow = (const f32x2*)(wf + c * 28);
      f32x2 vv; vv.x = var; vv.y = var;
#pragma unroll
      for (int u = 0; u < 14; ++u) wv[u] += wrow[u] * vv;
    }
  }

#pragma unroll
  for (int u = 0; u < 14; ++u) {
    int t0 = 2 * u;
    WV[t0 * DHW + idx] = __float2bfloat16(wv[u].x);
    if (t0 + 1 < 27) WV[(t0 + 1) * DHW + idx] = __float2bfloat16(wv[u].y);
  }
}

// ------------------------------------------------- K3a: 27-tap gather (conv)
__global__ __launch_bounds__(256) void k_conv(const __hip_bfloat16* __restrict__ WV,
                                              float* __restrict__ pre) {
  int idx = blockIdx.x * 256 + threadIdx.x;
  int x = idx % NW;
  int t1 = idx / NW;
  int y = t1 % NH;
  int d = t1 / NH;
  float acc = 0.f;
#pragma unroll
  for (int dd = 0; dd < 3; ++dd) {
    int dp = d + dd - 1;
    bool dok = (dp >= 0) && (dp < ND);
    int dpc = min(max(dp, 0), ND - 1);
#pragma unroll
    for (int i = 0; i < 3; ++i) {
      int yp = y + i - 1;
      bool yok = (yp >= 0) && (yp < NH);
      int ypc = min(max(yp, 0), NH - 1);
#pragma unroll
      for (int j = 0; j < 3; ++j) {
        int xp = x + j - 1;
        bool xok = (xp >= 0) && (xp < NW);
        int xpc = min(max(xp, 0), NW - 1);
        int t = dd * 9 + i * 3 + j;
        float v = __bfloat162float(WV[t * DHW + dpc * HW + ypc * NW + xpc]);
        acc += (dok && yok && xok) ? v : 0.f;
      }
    }
  }
  pre[idx] = acc;
}

// ---------------------------------------- K3b: softmax over D + depth + conf
__global__ __launch_bounds__(256) void k_softmax(const float* __restrict__ pre,
                                                 const float* __restrict__ depthv,
                                                 float* __restrict__ depthf,
                                                 float* __restrict__ out_depth,
                                                 float* __restrict__ out_conf) {
  int p = blockIdx.x * 256 + threadIdx.x;
  float pr[ND];
  float m = -1e30f;
#pragma unroll
  for (int d = 0; d < ND; ++d) { pr[d] = pre[d * HW + p]; m = fmaxf(m, pr[d]); }
  float s = 0.f;
#pragma unroll
  for (int d = 0; d < ND; ++d) { pr[d] = expf(pr[d] - m); s += pr[d]; }
  float inv = 1.f / s;
  float dep = 0.f, ti = 0.f;
#pragma unroll
  for (int d = 0; d < ND; ++d) {
    float prob = pr[d] * inv;
    pr[d] = prob;
    dep += prob * depthv[d];
    ti += prob * (float)d;
  }
  int di = (int)ti;
  di = di < 0 ? 0 : (di > ND - 1 ? ND - 1 : di);
  float conf = 0.f;
#pragma unroll
  for (int d = 0; d < ND; ++d)
    conf += (d >= di - 1 && d <= di + 2) ? pr[d] : 0.f;
  depthf[p] = dep;
  out_depth[p] = dep;
  out_conf[p] = conf;
}

// -------------------------------------------------- K4: convex upsample (x8)
// 8 outputs (dx 0..7) per thread: all mask loads lane-coalesced; depth taps
// shared across the 8 dx.
__global__ __launch_bounds__(256) void k_upsample(const float* __restrict__ mask,
                                                  const float* __restrict__ depthf,
                                                  float* __restrict__ out) {
  int idx = blockIdx.x * 256 + threadIdx.x;  // [0, HW*8)
  int x = idx % NW;
  int r = idx / NW;
  int y = r % NH;
  int dy = r / NH;                           // 0..7
  int pix = y * NW + x;

  float dv[9];
#pragma unroll
  for (int k = 0; k < 9; ++k) {
    int ky = y + k / 3 - 1;
    int kx = x + k % 3 - 1;
    bool ok = (ky >= 0) && (ky < NH) && (kx >= 0) && (kx < NW);
    int kyc = min(max(ky, 0), NH - 1);
    int kxc = min(max(kx, 0), NW - 1);
    float t = depthf[kyc * NW + kxc];
    dv[k] = ok ? t : 0.f;
  }

  float res[8];
#pragma unroll
  for (int dx = 0; dx < 8; ++dx) {
    float mv[9];
    float mmax = -1e30f;
#pragma unroll
    for (int k = 0; k < 9; ++k) {
      mv[k] = mask[(size_t)(k * 64 + dy * 8 + dx) * HW + pix];
      mmax = fmaxf(mmax, mv[k]);
    }
    float s = 0.f, acc = 0.f;
#pragma unroll
    for (int k = 0; k < 9; ++k) {
      float e = expf(mv[k] - mmax);
      s += e;
      acc += e * dv[k];
    }
    res[dx] = acc / s;
  }

  float* op = out + (size_t)(y * 8 + dy) * (NW * 8) + x * 8;
  f32x4 lo, hi;
  lo.x = res[0]; lo.y = res[1]; lo.z = res[2]; lo.w = res[3];
  hi.x = res[4]; hi.y = res[5]; hi.z = res[6]; hi.w = res[7];
  *(f32x4*)op = lo;
  *(f32x4*)(op + 4) = hi;
}

// ---------------------------------------------------------------- launcher
extern "C" void kernel_launch(void* const* d_in, const int* in_sizes, int n_in,
                              void* d_out, int out_size, void* d_ws, size_t ws_size,
                              hipStream_t stream) {
  const float* feat   = (const float*)d_in[0];
  const float* proj   = (const float*)d_in[1];
  const float* depthv = (const float*)d_in[2];
  const float* mask   = (const float*)d_in[3];
  const float* wreg   = (const float*)d_in[4];

  char* ws = (char*)d_ws;
  float* M       = (float*)(ws + OFF_M);
  float* wf      = (float*)(ws + OFF_WF);
  float* depthf  = (float*)(ws + OFF_DEPTHF);
  float* pre     = (float*)(ws + OFF_PRE);
  __hip_bfloat16* WV = (__hip_bfloat16*)(ws + OFF_WV);

  float* out = (float*)d_out;
  float* out_depth = out + (NH * 8) * (NW * 8);
  float* out_conf  = out_depth + HW;

  k_setup<<<1, 64, 0, stream>>>(proj, wreg, M, wf);
  k_warpvar<<<(NW / XSPAN) * NH, BTHREADS, 0, stream>>>(feat, depthv, M, wf, WV);
  k_conv<<<DHW / 256, 256, 0, stream>>>(WV, pre);
  k_softmax<<<HW / 256, 256, 0, stream>>>(pre, depthv, depthf, out_depth, out_conf);
  k_upsample<<<(NH * 8 * NW * 8 / 8) / 256, 256, 0, stream>>>(mask, depthf, out);
}

// Round 5
// 225.011 us; speedup vs baseline: 1.3543x; 1.3543x over previous
//
#include <hip/hip_runtime.h>
#include <hip/hip_bf16.h>

// Effi_MVS: B=1, V=5, C=32, D=48, H=128, W=160, RATIO=8.
// Round 8: R7 LDS staging regressed (FETCH 3x, serialization). R6 diagnosis:
// k_warpvar is MLP-starved (VGPR=52 -> compiler kept ~5 loads in flight;
// 35 cyc/load observed vs ~1/cyc service rate). Fixes:
//   - k_warpvar: R6 structure + explicit 8-channel load batching (f0[8],
//     e[8][4] register arrays, load phase separated from compute phase)
//     -> ~40 independent loads in flight per wave.
//   - k_conv: 8 outputs/thread; per (dd,i) tap-row a 10-wide x-window via
//     3x b128 + 2x u32 aligned loads (45 loads / 8 outputs vs 216); only
//     invalid x cases are x==-1 (x8==0) and x==160 (x8==152), masked.
// Everything else unchanged from R6 (best total 241 us, warpvar 139 us).

#define NV 5
#define NC 32
#define ND 48
#define NH 128
#define NW 160
#define HW (NH * NW)
#define DHW (ND * HW)

typedef __attribute__((ext_vector_type(2))) float f32x2;
typedef __attribute__((ext_vector_type(4))) float f32x4;
typedef __attribute__((ext_vector_type(2), aligned(4))) float f32x2u;
typedef __attribute__((ext_vector_type(8))) unsigned short u16x8;

// ws layout (bytes)
#define OFF_M      0          // float M[4][12]
#define OFF_WF     256        // float wf[32][28]
#define OFF_DEPTHF 4096       // float depthf[20480]
#define OFF_PRE    86016      // float pre[48*128*160]
#define OFF_WV     4018176    // bf16 WV[27][48*128*160]
// total = 57,102,336 bytes

__device__ __forceinline__ float bf2f(unsigned short u) {
  uint32_t b = ((uint32_t)u) << 16;
  float f;
  __builtin_memcpy(&f, &b, 4);
  return f;
}

// ---------------------------------------------------------------- K1: setup
__global__ void k_setup(const float* __restrict__ proj,
                        const float* __restrict__ wreg,
                        float* __restrict__ M, float* __restrict__ wf) {
  if (threadIdx.x != 0) return;
  double P[NV][2][4][4];
  for (int v = 0; v < NV; ++v)
    for (int m = 0; m < 2; ++m)
      for (int i = 0; i < 4; ++i)
        for (int j = 0; j < 4; ++j)
          P[v][m][i][j] = (double)proj[((v * 2 + m) * 4 + i) * 4 + j];
  double C[NV][4][4];
  for (int v = 0; v < NV; ++v) {
    for (int i = 0; i < 4; ++i)
      for (int j = 0; j < 4; ++j) C[v][i][j] = P[v][0][i][j];
    for (int i = 0; i < 3; ++i)
      for (int j = 0; j < 4; ++j) {
        double s = 0.0;
        for (int k = 0; k < 3; ++k) s += P[v][1][i][k] * P[v][0][k][j];
        C[v][i][j] = s;
      }
  }
  double a[4][8];
  for (int i = 0; i < 4; ++i)
    for (int j = 0; j < 4; ++j) { a[i][j] = C[0][i][j]; a[i][j + 4] = (i == j) ? 1.0 : 0.0; }
  for (int col = 0; col < 4; ++col) {
    int piv = col; double best = fabs(a[col][col]);
    for (int r = col + 1; r < 4; ++r) { double v = fabs(a[r][col]); if (v > best) { best = v; piv = r; } }
    if (piv != col)
      for (int j = 0; j < 8; ++j) { double t = a[col][j]; a[col][j] = a[piv][j]; a[piv][j] = t; }
    double pv = a[col][col];
    for (int j = 0; j < 8; ++j) a[col][j] /= pv;
    for (int r = 0; r < 4; ++r) if (r != col) {
      double f = a[r][col];
      for (int j = 0; j < 8; ++j) a[r][j] -= f * a[col][j];
    }
  }
  double inv[4][4];
  for (int i = 0; i < 4; ++i)
    for (int j = 0; j < 4; ++j) inv[i][j] = a[i][j + 4];
  for (int v = 1; v < NV; ++v) {
    float* m = M + (v - 1) * 12;
    for (int i = 0; i < 3; ++i) {
      double r[4] = {0, 0, 0, 0};
      for (int k = 0; k < 4; ++k) {
        double cv = C[v][i][k];
        for (int j = 0; j < 4; ++j) r[j] += cv * inv[k][j];
      }
      m[i * 3 + 0] = (float)r[0]; m[i * 3 + 1] = (float)r[1]; m[i * 3 + 2] = (float)r[2];
      m[9 + i] = (float)r[3];
    }
  }
  for (int c = 0; c < NC; ++c) {
    for (int t = 0; t < 27; ++t) wf[c * 28 + t] = wreg[c * 27 + t];
    wf[c * 28 + 27] = 0.f;
  }
}

// ------------------------------------------- K2: warp + variance + contract
__global__ __launch_bounds__(256) void k_warpvar(
    const float* __restrict__ feat,    // [5][32][128][160]
    const float* __restrict__ depthv,  // [48]
    const float* __restrict__ M,       // [4][12]
    const float* __restrict__ wf,      // [32][28]
    __hip_bfloat16* __restrict__ WV)   // [27][DHW]
{
  int idx = blockIdx.x * 256 + threadIdx.x;   // [0, DHW)
  int x = idx % NW;
  int t1 = idx / NW;
  int y = t1 % NH;
  int d = t1 / NH;
  int pix = y * NW + x;
  float xf = (float)x, yf = (float)y;
  float df = depthv[d];

  int   off[4];
  float wA[4], wB[4];
  bool any4 = false;

#pragma unroll
  for (int v = 0; v < 4; ++v) {
    const float* m = M + v * 12;
    float rx = m[0] * xf + m[1] * yf + m[2];
    float ry = m[3] * xf + m[4] * yf + m[5];
    float rz = m[6] * xf + m[7] * yf + m[8];
    float px = rx * df + m[9];
    float py = ry * df + m[10];
    float pz = rz * df + m[11];
    float gx = px / pz;
    float gy = py / pz;
    float y0 = floorf(gy);
    float wy = gy - y0;
    bool two = (wy == 0.f) || (wy == 1.f);
    any4 = any4 || !two;
    float rowf = (wy == 0.f) ? y0 : (y0 + 1.f);  // single surviving y-row
    float x0 = floorf(gx);
    float wx = gx - x0;
    bool yok  = (rowf >= 0.f) && (rowf <= (float)(NH - 1));
    bool x0ok = (x0 >= 0.f) && (x0 <= (float)(NW - 1)) && yok;
    bool x1ok = (x0 >= -1.f) && (x0 <= (float)(NW - 2)) && yok;
    float rc = fminf(fmaxf(rowf, 0.f), (float)(NH - 1));
    float xc = fminf(fmaxf(x0, 0.f), (float)(NW - 1));
    int xi = (int)xc;
    int o = (int)rc * NW + xi;
    bool ddv = (o == HW - 1);          // absolute plane end: shift base by 1
    bool sv  = (x0 >= 0.f) && (xi <= NW - 2);  // e.y is a distinct valid tap1
    o -= ddv ? 1 : 0;
    float w0 = (1.f - wx) * (x0ok ? 1.f : 0.f);
    float w1 = wx * (x1ok ? 1.f : 0.f);
    float wsum = w0 + w1;
    wA[v] = ddv ? 0.f : (sv ? w0 : wsum);
    wB[v] = ddv ? wsum : (sv ? w1 : 0.f);
    off[v] = o;
  }

  f32x2 wv[14];
#pragma unroll
  for (int u = 0; u < 14; ++u) { wv[u].x = 0.f; wv[u].y = 0.f; }

  if (__builtin_expect(any4, 0)) {
    // ---------- general 4-tap fallback (cold). v/u unrolled, c rolled.
    int cidx[16]; float cw[16];
#pragma unroll
    for (int v = 0; v < 4; ++v) {
      const float* m = M + v * 12;
      float rx = m[0] * xf + m[1] * yf + m[2];
      float ry = m[3] * xf + m[4] * yf + m[5];
      float rz = m[6] * xf + m[7] * yf + m[8];
      float px = rx * df + m[9];
      float py = ry * df + m[10];
      float pz = rz * df + m[11];
      float gx = px / pz;
      float gy = py / pz;
      float x0 = floorf(gx), y0 = floorf(gy);
      float wx = gx - x0, wy = gy - y0;
      float cxs[2] = {x0, x0 + 1.f}, cys[2] = {y0, y0 + 1.f};
      float wxs[2] = {1.f - wx, wx}, wys[2] = {1.f - wy, wy};
#pragma unroll
      for (int cy = 0; cy < 2; ++cy)
#pragma unroll
        for (int cx = 0; cx < 2; ++cx) {
          float fx = cxs[cx], fy = cys[cy];
          bool valid = (fx >= 0.f) && (fx <= (float)(NW - 1)) &&
                       (fy >= 0.f) && (fy <= (float)(NH - 1));
          float fxc = fminf(fmaxf(fx, 0.f), (float)(NW - 1));
          float fyc = fminf(fmaxf(fy, 0.f), (float)(NH - 1));
          int xi2 = (int)fxc, yi2 = (int)fyc;
          cidx[v * 4 + cy * 2 + cx] = yi2 * NW + xi2;
          cw[v * 4 + cy * 2 + cx] = wxs[cx] * wys[cy] * (valid ? 1.f : 0.f);
        }
    }
    for (int c = 0; c < NC; ++c) {
      float f0 = feat[c * HW + pix];
      float vs = f0, vq = f0 * f0;
#pragma unroll
      for (int v = 0; v < 4; ++v) {
        const float* fv = feat + ((v + 1) * NC + c) * HW;
        float val = cw[v * 4 + 0] * fv[cidx[v * 4 + 0]]
                  + cw[v * 4 + 1] * fv[cidx[v * 4 + 1]]
                  + cw[v * 4 + 2] * fv[cidx[v * 4 + 2]]
                  + cw[v * 4 + 3] * fv[cidx[v * 4 + 3]];
        vs += val;
        vq += val * val;
      }
      float var = vq * 0.2f - (vs * 0.2f) * (vs * 0.2f);
      const f32x2* wrow = (const f32x2*)(wf + c * 28);
      f32x2 vv; vv.x = var; vv.y = var;
#pragma unroll
      for (int u = 0; u < 14; ++u) wv[u] += wrow[u] * vv;
    }
  } else {
    // ---------- hot 2-tap path, 8-channel load batches for MLP
#pragma unroll
    for (int g = 0; g < NC; g += 8) {
      float f0[8];
      f32x2 e[8][4];
      // load phase: 40 independent loads issued before any use
#pragma unroll
      for (int cc = 0; cc < 8; ++cc) {
        int c = g + cc;
        f0[cc] = feat[c * HW + pix];
#pragma unroll
        for (int v = 0; v < 4; ++v) {
          const float* fv = feat + ((v + 1) * NC + c) * HW;
          f32x2u t = *(const f32x2u*)(fv + off[v]);
          e[cc][v].x = t.x; e[cc][v].y = t.y;
        }
      }
      // compute phase
#pragma unroll
      for (int cc = 0; cc < 8; ++cc) {
        int c = g + cc;
        float vs = f0[cc], vq = f0[cc] * f0[cc];
#pragma unroll
        for (int v = 0; v < 4; ++v) {
          float val = wA[v] * e[cc][v].x + wB[v] * e[cc][v].y;
          vs += val;
          vq += val * val;
        }
        float var = vq * 0.2f - (vs * 0.2f) * (vs * 0.2f);
        const f32x2* wrow = (const f32x2*)(wf + c * 28);
        f32x2 vv; vv.x = var; vv.y = var;
#pragma unroll
        for (int u = 0; u < 14; ++u) wv[u] += wrow[u] * vv;
      }
    }
  }

#pragma unroll
  for (int u = 0; u < 14; ++u) {
    int t0 = 2 * u;
    WV[t0 * DHW + idx] = __float2bfloat16(wv[u].x);
    if (t0 + 1 < 27) WV[(t0 + 1) * DHW + idx] = __float2bfloat16(wv[u].y);
  }
}

// ------------------------------------------------- K3a: 27-tap gather (conv)
// 8 consecutive-x outputs per thread. Per (dd,i): three tap-planes (j=0,1,2),
// x-window [x8-1, x8+8]: b128 at x8 (elems 0..7) per plane, u32 at x8-2
// (elem -1, j=0 plane), u32 at x8+8 (elem 8, j=2 plane). Only possible
// invalid x are x==-1 (when x8==0) and x==160 (when x8==152) -> masked.
__global__ __launch_bounds__(256) void k_conv(const __hip_bfloat16* __restrict__ WV,
                                              float* __restrict__ pre) {
  int t8 = blockIdx.x * 256 + threadIdx.x;   // [0, DHW/8)
  int x8 = (t8 % (NW / 8)) * 8;
  int r = t8 / (NW / 8);
  int y = r % NH;
  int d = r / NH;

  bool lo_ok = (x8 > 0);
  bool hi_ok = (x8 < NW - 8);
  int xlo = lo_ok ? x8 - 2 : 0;        // aligned 4B; value masked if clamped
  int xhi = hi_ok ? x8 + 8 : NW - 8;   // aligned 4B; value masked if clamped

  float acc[8];
#pragma unroll
  for (int k = 0; k < 8; ++k) acc[k] = 0.f;

#pragma unroll
  for (int dd = 0; dd < 3; ++dd) {
    int dp = d + dd - 1;
    bool dok = (dp >= 0) && (dp < ND);
    int dpc = min(max(dp, 0), ND - 1);
#pragma unroll
    for (int i = 0; i < 3; ++i) {
      int yp = y + i - 1;
      bool yok = (yp >= 0) && (yp < NH);
      int ypc = min(max(yp, 0), NH - 1);
      float gok = (dok && yok) ? 1.f : 0.f;
      const __hip_bfloat16* base =
          WV + (size_t)(dd * 9 + i * 3) * DHW + (size_t)dpc * HW + ypc * NW;

      // j = 0 plane: elems -1..6
      u16x8 m0 = *(const u16x8*)(base + x8);
      uint32_t l0; __builtin_memcpy(&l0, base + xlo, 4);
      // j = 1 plane: elems 0..7
      u16x8 m1 = *(const u16x8*)(base + DHW + x8);
      // j = 2 plane: elems 1..8
      u16x8 m2 = *(const u16x8*)(base + 2 * (size_t)DHW + x8);
      uint32_t h2; __builtin_memcpy(&h2, base + 2 * (size_t)DHW + xhi, 4);

      float em1 = lo_ok ? bf2f((unsigned short)(l0 >> 16)) : 0.f;
      float e8  = hi_ok ? bf2f((unsigned short)(h2 & 0xffff)) : 0.f;

      acc[0] += gok * (em1 + bf2f(m1[0]) + bf2f(m2[1]));
#pragma unroll
      for (int k = 1; k < 7; ++k)
        acc[k] += gok * (bf2f(m0[k - 1]) + bf2f(m1[k]) + bf2f(m2[k + 1]));
      acc[7] += gok * (bf2f(m0[6]) + bf2f(m1[7]) + e8);
    }
  }

  float* op = pre + (size_t)d * HW + y * NW + x8;
  f32x4 lo4, hi4;
  lo4.x = acc[0]; lo4.y = acc[1]; lo4.z = acc[2]; lo4.w = acc[3];
  hi4.x = acc[4]; hi4.y = acc[5]; hi4.z = acc[6]; hi4.w = acc[7];
  *(f32x4*)op = lo4;
  *(f32x4*)(op + 4) = hi4;
}

// ---------------------------------------- K3b: softmax over D + depth + conf
__global__ __launch_bounds__(256) void k_softmax(const float* __restrict__ pre,
                                                 const float* __restrict__ depthv,
                                                 float* __restrict__ depthf,
                                                 float* __restrict__ out_depth,
                                                 float* __restrict__ out_conf) {
  int p = blockIdx.x * 256 + threadIdx.x;
  float pr[ND];
  float m = -1e30f;
#pragma unroll
  for (int d = 0; d < ND; ++d) { pr[d] = pre[d * HW + p]; m = fmaxf(m, pr[d]); }
  float s = 0.f;
#pragma unroll
  for (int d = 0; d < ND; ++d) { pr[d] = expf(pr[d] - m); s += pr[d]; }
  float inv = 1.f / s;
  float dep = 0.f, ti = 0.f;
#pragma unroll
  for (int d = 0; d < ND; ++d) {
    float prob = pr[d] * inv;
    pr[d] = prob;
    dep += prob * depthv[d];
    ti += prob * (float)d;
  }
  int di = (int)ti;
  di = di < 0 ? 0 : (di > ND - 1 ? ND - 1 : di);
  float conf = 0.f;
#pragma unroll
  for (int d = 0; d < ND; ++d)
    conf += (d >= di - 1 && d <= di + 2) ? pr[d] : 0.f;
  depthf[p] = dep;
  out_depth[p] = dep;
  out_conf[p] = conf;
}

// -------------------------------------------------- K4: convex upsample (x8)
__global__ __launch_bounds__(256) void k_upsample(const float* __restrict__ mask,
                                                  const float* __restrict__ depthf,
                                                  float* __restrict__ out) {
  int idx = blockIdx.x * 256 + threadIdx.x;  // [0, HW*8)
  int x = idx % NW;
  int r = idx / NW;
  int y = r % NH;
  int dy = r / NH;                           // 0..7
  int pix = y * NW + x;

  float dv[9];
#pragma unroll
  for (int k = 0; k < 9; ++k) {
    int ky = y + k / 3 - 1;
    int kx = x + k % 3 - 1;
    bool ok = (ky >= 0) && (ky < NH) && (kx >= 0) && (kx < NW);
    int kyc = min(max(ky, 0), NH - 1);
    int kxc = min(max(kx, 0), NW - 1);
    float t = depthf[kyc * NW + kxc];
    dv[k] = ok ? t : 0.f;
  }

  float res[8];
#pragma unroll
  for (int dx = 0; dx < 8; ++dx) {
    float mv[9];
    float mmax = -1e30f;
#pragma unroll
    for (int k = 0; k < 9; ++k) {
      mv[k] = mask[(size_t)(k * 64 + dy * 8 + dx) * HW + pix];
      mmax = fmaxf(mmax, mv[k]);
    }
    float s = 0.f, acc = 0.f;
#pragma unroll
    for (int k = 0; k < 9; ++k) {
      float e = expf(mv[k] - mmax);
      s += e;
      acc += e * dv[k];
    }
    res[dx] = acc / s;
  }

  float* op = out + (size_t)(y * 8 + dy) * (NW * 8) + x * 8;
  f32x4 lo, hi;
  lo.x = res[0]; lo.y = res[1]; lo.z = res[2]; lo.w = res[3];
  hi.x = res[4]; hi.y = res[5]; hi.z = res[6]; hi.w = res[7];
  *(f32x4*)op = lo;
  *(f32x4*)(op + 4) = hi;
}

// ---------------------------------------------------------------- launcher
extern "C" void kernel_launch(void* const* d_in, const int* in_sizes, int n_in,
                              void* d_out, int out_size, void* d_ws, size_t ws_size,
                              hipStream_t stream) {
  const float* feat   = (const float*)d_in[0];
  const float* proj   = (const float*)d_in[1];
  const float* depthv = (const float*)d_in[2];
  const float* mask   = (const float*)d_in[3];
  const float* wreg   = (const float*)d_in[4];

  char* ws = (char*)d_ws;
  float* M       = (float*)(ws + OFF_M);
  float* wf      = (float*)(ws + OFF_WF);
  float* depthf  = (float*)(ws + OFF_DEPTHF);
  float* pre     = (float*)(ws + OFF_PRE);
  __hip_bfloat16* WV = (__hip_bfloat16*)(ws + OFF_WV);

  float* out = (float*)d_out;
  float* out_depth = out + (NH * 8) * (NW * 8);
  float* out_conf  = out_depth + HW;

  k_setup<<<1, 64, 0, stream>>>(proj, wreg, M, wf);
  k_warpvar<<<DHW / 256, 256, 0, stream>>>(feat, depthv, M, wf, WV);
  k_conv<<<(DHW / 8) / 256, 256, 0, stream>>>(WV, pre);
  k_softmax<<<HW / 256, 256, 0, stream>>>(pre, depthv, depthf, out_depth, out_conf);
  k_upsample<<<(NH * 8 * NW * 8 / 8) / 256, 256, 0, stream>>>(mask, depthf, out);
}